// Round 6
// baseline (177.249 us; speedup 1.0000x reference)
//
#include <hip/hip_runtime.h>
#include <math.h>

// Problem constants
#define KC 1024       // num codes
#define DD 256        // embedding dim
#define NROWS 32768   // 32 * 32 * 32 (B*H*W)
#define NELEM 8388608 // NROWS * DD

typedef _Float16 f16;
typedef __attribute__((ext_vector_type(8))) _Float16 f16x8;
typedef __attribute__((ext_vector_type(16))) float f32x16;

#define KEY_SCALE 2097152.0f   // 2^21; |score| <= ~0.63 -> |ikey| < 2^21
#define KEY_INV   (1.0f / 2097152.0f)

// ---------------------------------------------------------------------------
// prep: zero counts/loss64/done + c_sq (exact fp32) + emb -> fp16 swizzled
// grid 256 x 256.  emb_h layout: [kg 32][code 1024][8]
// ---------------------------------------------------------------------------
__global__ void vq_prep_kernel(const float* __restrict__ emb, f16* __restrict__ emb_h,
                               float* __restrict__ c_sq, int* __restrict__ counts,
                               float* __restrict__ loss64, unsigned* __restrict__ done) {
    const int tid = threadIdx.x;
    const int gt = blockIdx.x * 256 + tid;
    if (gt < KC) counts[gt] = 0;
    if (gt < 64) loss64[gt] = 0.0f;
    if (gt == 0) *done = 0u;
    {
        int k = blockIdx.x * 4 + (tid >> 6);
        int lane = tid & 63;
        float4 v = *(const float4*)(emb + (size_t)k * DD + lane * 4);
        float s = v.x * v.x + v.y * v.y + v.z * v.z + v.w * v.w;
        #pragma unroll
        for (int off = 32; off > 0; off >>= 1) s += __shfl_down(s, off);
        if (lane == 0) c_sq[k] = s;
    }
    if (gt < 32768) {
        int code = gt & 1023;
        int kg = gt >> 10;
        const float* p = emb + (size_t)code * DD + kg * 8;
        float4 v0 = *(const float4*)p;
        float4 v1 = *(const float4*)(p + 4);
        f16x8 hcv;
        hcv[0] = (f16)v0.x; hcv[1] = (f16)v0.y; hcv[2] = (f16)v0.z; hcv[3] = (f16)v0.w;
        hcv[4] = (f16)v1.x; hcv[5] = (f16)v1.y; hcv[6] = (f16)v1.z; hcv[7] = (f16)v1.w;
        *(f16x8*)(emb_h + (size_t)gt * 8) = hcv;
    }
}

// ---------------------------------------------------------------------------
// K1: argmin producer. grid 512, 1024 threads (16 waves), 64 rows/block,
// all 1024 codes -> no cross-block sync. Wave w owns codes [w*64,(w+1)*64)
// as 2 sequential 32-code chunks; per chunk a 2x1 register block (rows 0-31
// and 32-63 share the b-fragment). Persistent in-loop state ~55 unified regs
// (2 accs=32 + frags + addrs); launch_bounds(1024,8) forces <=64 ->
// 8 waves/SIMD -> 2 blocks x 16 waves = 32 waves/CU (vs R5's grid-capped 16).
// Per-block emb_h L2 draw stays 512 KB (codes partitioned across waves).
// Outputs: idx_g (plain stores), counts (atomicAdd), loss64 partials.
// argmin key = trunc(score*2^21)*1024 + code (monotone, first-min ties;
// bit-identical to prior rounds -> identical idx).
// loss per row: sum_c (q-z)^2 = score_min + ||z||^2.
// ---------------------------------------------------------------------------
__global__ __launch_bounds__(1024, 8)
void vq_argmin_kernel(const float* __restrict__ z, const f16* __restrict__ emb_h,
                      const float* __restrict__ c_sq, int* __restrict__ counts,
                      float* __restrict__ loss64, int* __restrict__ idx_g) {
    __shared__ __align__(16) f16 z_s[32 * 64 * 8];   // [kg 32][row 64][8] = 32768 B
    __shared__ int   bl_key[16][64];                  // 4096 B
    __shared__ float zsq_part[16][64];                // 4096 B

    const int tid = threadIdx.x;
    const int n0 = blockIdx.x * 64;
    const int b = n0 >> 10;
    const int hw0 = n0 & 1023;

    ((int*)bl_key)[tid] = 0x7FFFFFFF;   // 1024 ints, one per thread

    // ---- Phase A: stage z tile fp16 + per-row ||z||^2 partials ----
    {
        const int r = tid & 63;
        const int kq = tid >> 6;  // 0..15, each covers 16 channels (2 kgs)
        const float* zp = z + (size_t)b * (DD * 1024) + hw0 + r;
        float sq = 0.f;
        #pragma unroll
        for (int it = 0; it < 2; ++it) {
            int kg = kq * 2 + it;
            f16x8 hv;
            #pragma unroll
            for (int j = 0; j < 8; ++j) {
                float v = zp[(size_t)(kg * 8 + j) * 1024];
                sq += v * v;
                hv[j] = (f16)v;
            }
            *(f16x8*)&z_s[(kg * 64 + r) * 8] = hv;
        }
        zsq_part[kq][r] = sq;
    }
    __syncthreads();

    const int m = tid & 31;        // code-lane within 32-tile
    const int h = (tid >> 5) & 1;  // k-half (lane property)
    const int w = tid >> 6;        // wave id 0..15

    // ---- Phase B: 2 chunks x (2 row-tiles) register block ----
    for (int c = 0; c < 2; ++c) {
        const int code = w * 64 + c * 32 + m;
        const f16* ebp = emb_h + (size_t)h * 8192 + (size_t)code * 8;

        f32x16 acc0, acc1;   // rows m / rows m+32
        #pragma unroll
        for (int i = 0; i < 16; ++i) { acc0[i] = 0.f; acc1[i] = 0.f; }

        #pragma unroll 2
        for (int ks = 0; ks < 16; ++ks) {
            const f16* za = z_s + ((size_t)(2 * ks + h) * 64 + m) * 8;
            f16x8 a0 = *(const f16x8*)(za);            // rows m
            f16x8 a1 = *(const f16x8*)(za + 256);      // rows m+32
            f16x8 b0 = *(const f16x8*)(ebp + (size_t)ks * 16384);
            acc0 = __builtin_amdgcn_mfma_f32_32x32x16_f16(a0, b0, acc0, 0, 0, 0);
            acc1 = __builtin_amdgcn_mfma_f32_32x32x16_f16(a1, b0, acc1, 0, 0, 0);
        }

        const float cs = c_sq[code];
        int bk0[16], bk1[16];
        #pragma unroll
        for (int reg = 0; reg < 16; ++reg) {
            float s0 = fmaf(-2.f, acc0[reg], cs);
            float s1 = fmaf(-2.f, acc1[reg], cs);
            bk0[reg] = (int)(s0 * KEY_SCALE) * 1024 + code;
            bk1[reg] = (int)(s1 * KEY_SCALE) * 1024 + code;
        }

        // butterfly min across the 32 code-lanes (h halves carry distinct rows)
        #pragma unroll
        for (int s = 0; s < 16; ++s) {
            int k0 = bk0[s], k1 = bk1[s];
            #pragma unroll
            for (int d = 16; d >= 1; d >>= 1) {
                k0 = min(k0, __shfl_xor(k0, d));
                k1 = min(k1, __shfl_xor(k1, d));
            }
            bk0[s] = k0; bk1[s] = k1;
        }
        if (m == 0) {
            #pragma unroll
            for (int s = 0; s < 16; ++s) {
                int row = (s & 3) + 8 * (s >> 2) + 4 * h;
                bl_key[w][row]      = min(bl_key[w][row],      bk0[s]);
                bl_key[w][32 + row] = min(bl_key[w][32 + row], bk1[s]);
            }
        }
    }
    __syncthreads();

    // ---- combine 16 waves -> idx store + counts + loss partial, then exit
    if (tid < 64) {
        int k = bl_key[0][tid];
        #pragma unroll
        for (int w2 = 1; w2 < 16; ++w2) k = min(k, bl_key[w2][tid]);
        int i = k & 1023;               // low 10 bits = code (two's complement safe)
        idx_g[n0 + tid] = i;
        atomicAdd(&counts[i], 1);
        float zq = 0.f;
        #pragma unroll
        for (int p2 = 0; p2 < 16; ++p2) zq += zsq_part[p2][tid];
        float lr = (float)(k >> 10) * KEY_INV + zq;  // score_min + ||z||^2
        #pragma unroll
        for (int off = 32; off > 0; off >>= 1) lr += __shfl_down(lr, off);
        if (tid == 0) atomicAdd(&loss64[blockIdx.x & 63], lr);
    }
}

// ---------------------------------------------------------------------------
// K2: consumer. grid 1024 = (tile 0..511) x (channel-half 0..1), 512 threads.
// Single-pass transposed LDS staging Qt[128][65] (pad 65 -> both the scatter
// writes and the column drain reads are bank-conflict-free). Each block
// writes 64 rows x 128 channels of out in full 256B lines. 33.6KB LDS ->
// 4 blocks/CU. Last of 1024 blocks finalizes loss + perplexity.
// ---------------------------------------------------------------------------
__global__ __launch_bounds__(512, 8)
void vq_out_kernel(const float* __restrict__ emb, const int* __restrict__ idx_g,
                   const int* __restrict__ counts, const float* __restrict__ loss64,
                   unsigned* __restrict__ done, float* __restrict__ out,
                   float* __restrict__ out_tail) {
    __shared__ float Qt[128][65];   // 33280 B, transposed: [ch][row]
    __shared__ int   idx_s[64];
    __shared__ float wsum[8];
    __shared__ int   flag_s;

    const int tid = threadIdx.x;
    const int tile = blockIdx.x >> 1;
    const int ch0 = (blockIdx.x & 1) * 128;
    const int n0 = tile * 64;
    const int b = n0 >> 10;
    const int hw0 = n0 & 1023;

    if (tid < 64) idx_s[tid] = idx_g[n0 + tid];
    __syncthreads();

    // stage: thread (p=tid>>6 in 0..7, r=tid&63) loads emb[idx[r]][ch0+p*16..+16]
    // as 4 x float4 (coalesced 64B/lane from L2), scatters into Qt columns.
    {
        int r = tid & 63;
        int p = tid >> 6;
        const float* ep = emb + (size_t)idx_s[r] * DD + ch0 + p * 16;
        float4 v0 = *(const float4*)(ep);
        float4 v1 = *(const float4*)(ep + 4);
        float4 v2 = *(const float4*)(ep + 8);
        float4 v3 = *(const float4*)(ep + 12);
        float vv[16] = {v0.x, v0.y, v0.z, v0.w, v1.x, v1.y, v1.z, v1.w,
                        v2.x, v2.y, v2.z, v2.w, v3.x, v3.y, v3.z, v3.w};
        #pragma unroll
        for (int g = 0; g < 16; ++g)
            Qt[p * 16 + g][r] = vv[g];   // lanes r consecutive -> conflict-free
    }
    __syncthreads();

    // drain: wave w covers channels [w*16,(w+1)*16); per channel the 64 lanes
    // write one full 256B contiguous line of out.
    {
        int lane = tid & 63;
        int w = tid >> 6;
        const size_t base = (size_t)b * (DD * 1024) + hw0 + lane;
        #pragma unroll
        for (int g = 0; g < 16; ++g) {
            int ch = w * 16 + g;
            out[base + (size_t)(ch0 + ch) * 1024] = Qt[ch][lane];
        }
    }

    // ---- last-block finalize ----
    if (tid == 0) {
        __threadfence();
        flag_s = (atomicAdd(done, 1u) == 1023u) ? 1 : 0;
    }
    __syncthreads();
    if (flag_s) {
        float s = 0.f;
        for (int k = tid; k < KC; k += 512) {
            float pr = (float)counts[k] * (1.0f / (float)NROWS);
            s += pr * logf(pr + 1e-10f);
        }
        #pragma unroll
        for (int off = 32; off > 0; off >>= 1) s += __shfl_down(s, off);
        if ((tid & 63) == 0) wsum[tid >> 6] = s;
        __syncthreads();
        float loss_tot = 0.f;
        if (tid < 64) {
            float lv = loss64[tid];
            #pragma unroll
            for (int off = 32; off > 0; off >>= 1) lv += __shfl_down(lv, off);
            loss_tot = lv;              // lane 0 (tid 0) valid
        }
        if (tid == 0) {
            float ent = 0.f;
            #pragma unroll
            for (int p = 0; p < 8; ++p) ent += wsum[p];
            out_tail[0] = 1.25f * loss_tot * (1.0f / (float)NELEM);
            out_tail[1] = expf(-ent);
        }
    }
}

// ---------------------------------------------------------------------------
extern "C" void kernel_launch(void* const* d_in, const int* in_sizes, int n_in,
                              void* d_out, int out_size, void* d_ws, size_t ws_size,
                              hipStream_t stream) {
    const float* z = (const float*)d_in[0];    // (32,256,32,32)
    const float* emb = (const float*)d_in[1];  // (1024,256)
    float* out = (float*)d_out;                // 8388608 + 2

    char* wsb = (char*)d_ws;
    f16* emb_h = (f16*)wsb;                        // 524288 B
    float* c_sq = (float*)(wsb + 524288);          // 4096 B
    int* counts = (int*)(wsb + 528384);            // 4096 B
    float* loss64 = (float*)(wsb + 532480);        // 256 B
    unsigned* done = (unsigned*)(wsb + 532736);    // 4 B
    int* idx_g = (int*)(wsb + 535040);             // 131072 B

    hipLaunchKernelGGL(vq_prep_kernel, dim3(256), dim3(256), 0, stream,
                       emb, emb_h, c_sq, counts, loss64, done);
    hipLaunchKernelGGL(vq_argmin_kernel, dim3(512), dim3(1024), 0, stream,
                       z, emb_h, c_sq, counts, loss64, idx_g);
    hipLaunchKernelGGL(vq_out_kernel, dim3(1024), dim3(512), 0, stream,
                       emb, idx_g, counts, loss64, done, out, out + NELEM);
}

// Round 7
// 157.796 us; speedup vs baseline: 1.1233x; 1.1233x over previous
//
#include <hip/hip_runtime.h>
#include <math.h>

// Problem constants
#define KC 1024       // num codes
#define DD 256        // embedding dim
#define NROWS 32768   // 32 * 32 * 32 (B*H*W)
#define NELEM 8388608 // NROWS * DD

typedef _Float16 f16;
typedef __attribute__((ext_vector_type(8))) _Float16 f16x8;
typedef __attribute__((ext_vector_type(16))) float f32x16;

#define KEY_SCALE 2097152.0f   // 2^21; |score| <= ~0.63 -> |ikey| < 2^21
#define KEY_INV   (1.0f / 2097152.0f)

// ---------------------------------------------------------------------------
// prep: zero counts/loss64/done + key_ws=INT_MAX + c_sq (exact fp32) +
// emb -> fp16 swizzled.  grid 256 x 256.  emb_h layout: [kg 32][code 1024][8]
// ---------------------------------------------------------------------------
__global__ void vq_prep_kernel(const float* __restrict__ emb, f16* __restrict__ emb_h,
                               float* __restrict__ c_sq, int* __restrict__ counts,
                               float* __restrict__ loss64, unsigned* __restrict__ done,
                               int* __restrict__ key_ws) {
    const int tid = threadIdx.x;
    const int gt = blockIdx.x * 256 + tid;
    if (gt < KC) counts[gt] = 0;
    if (gt < 64) loss64[gt] = 0.0f;
    if (gt == 0) *done = 0u;
    if (gt < 32768) key_ws[gt] = 0x7FFFFFFF;
    {
        int k = blockIdx.x * 4 + (tid >> 6);
        int lane = tid & 63;
        float4 v = *(const float4*)(emb + (size_t)k * DD + lane * 4);
        float s = v.x * v.x + v.y * v.y + v.z * v.z + v.w * v.w;
        #pragma unroll
        for (int off = 32; off > 0; off >>= 1) s += __shfl_down(s, off);
        if (lane == 0) c_sq[k] = s;
    }
    if (gt < 32768) {
        int code = gt & 1023;
        int kg = gt >> 10;
        const float* p = emb + (size_t)code * DD + kg * 8;
        float4 v0 = *(const float4*)p;
        float4 v1 = *(const float4*)(p + 4);
        f16x8 hcv;
        hcv[0] = (f16)v0.x; hcv[1] = (f16)v0.y; hcv[2] = (f16)v0.z; hcv[3] = (f16)v0.w;
        hcv[4] = (f16)v1.x; hcv[5] = (f16)v1.y; hcv[6] = (f16)v1.z; hcv[7] = (f16)v1.w;
        *(f16x8*)(emb_h + (size_t)gt * 8) = hcv;
    }
}

// ---------------------------------------------------------------------------
// K1: argmin producer, SWAPPED-OPERAND MFMA.
//   mfma(emb_frag, z_frag): D[code][zrow] -> col=lane = z row, row=reg = code.
//   Argmin over codes is now IN-REGISTER (16 mins, consumed immediately; no
//   bk[] arrays, no 5-step butterflies) + one shfl_xor(32) to merge halves.
//   Fragments are loaded identically to the unswapped version (same lane
//   layout for A and B) -> bit-identical scores/keys/argmin.
// grid 1024 = (tile 0..511) x (code-half cg), 512 threads (8 waves).
//   Pair blocks (bid, bid+512) share a tile: same XCD (512%8==0) -> second
//   z stage hits L2. emb_h aggregate L2 draw stays 256MB (each block reads
//   half). In-loop state ~56 regs -> launch_bounds(512,8) honest -> 8
//   waves/SIMD, 4 blocks/CU (LDS 36.9KB), 32 waves/CU.
// Cross-block argmin combine: atomicMin into key_ws (associative, exact).
// cg==0 blocks also write zsq_g (per-row ||z||^2) for K2's loss.
// ---------------------------------------------------------------------------
__global__ __launch_bounds__(512, 8)
void vq_argmin_kernel(const float* __restrict__ z, const f16* __restrict__ emb_h,
                      const float* __restrict__ c_sq, float* __restrict__ zsq_g,
                      int* __restrict__ key_ws) {
    __shared__ __align__(16) f16 z_s[32 * 64 * 8];   // [kg 32][row 64][8] = 32768 B
    __shared__ int   bl_key[8][64];                   // 2048 B
    __shared__ float zsq_part[8][64];                 // 2048 B

    const int tid = threadIdx.x;
    const int bid = blockIdx.x;
    const int tile = bid & 511;
    const int cg = bid >> 9;       // code-half: codes [cg*512, cg*512+512)
    const int n0 = tile * 64;
    const int b = n0 >> 10;
    const int hw0 = n0 & 1023;

    // ---- Phase A: stage z tile fp16 + per-row ||z||^2 partials ----
    {
        const int r = tid & 63;
        const int kq = tid >> 6;  // 0..7
        const float* zp = z + (size_t)b * (DD * 1024) + hw0 + r;
        float sq = 0.f;
        #pragma unroll
        for (int it = 0; it < 4; ++it) {
            int kg = kq * 4 + it;
            f16x8 hv;
            #pragma unroll
            for (int j = 0; j < 8; ++j) {
                float v = zp[(size_t)(kg * 8 + j) * 1024];
                sq += v * v;
                hv[j] = (f16)v;
            }
            *(f16x8*)&z_s[(kg * 64 + r) * 8] = hv;
        }
        zsq_part[kq][r] = sq;
    }
    __syncthreads();

    const int m = tid & 31;        // lane -> z row (D col)
    const int h = (tid >> 5) & 1;  // k-half; also selects code subset (+4h)
    const int w = tid >> 6;        // wave id 0..7

    int kmin0 = 0x7FFFFFFF;        // running key, rows m
    int kmin1 = 0x7FFFFFFF;        // running key, rows m+32

    // ---- Phase B: wave owns 64 codes as 2 chunks of 32 ----
    for (int c = 0; c < 2; ++c) {
        const int cb = cg * 512 + w * 64 + c * 32;     // chunk base code
        const f16* ebp = emb_h + (size_t)h * 8192 + (size_t)(cb + m) * 8;

        f32x16 acc0, acc1;   // D[code][row] for z rows 0-31 / 32-63
        #pragma unroll
        for (int i = 0; i < 16; ++i) { acc0[i] = 0.f; acc1[i] = 0.f; }

        #pragma unroll 2
        for (int ks = 0; ks < 16; ++ks) {
            const f16* za = z_s + ((size_t)(2 * ks + h) * 64 + m) * 8;
            f16x8 zb0 = *(const f16x8*)(za);           // z rows 0-31  (B frag)
            f16x8 zb1 = *(const f16x8*)(za + 256);     // z rows 32-63 (B frag)
            f16x8 ea  = *(const f16x8*)(ebp + (size_t)ks * 16384); // emb (A frag)
            acc0 = __builtin_amdgcn_mfma_f32_32x32x16_f16(ea, zb0, acc0, 0, 0, 0);
            acc1 = __builtin_amdgcn_mfma_f32_32x32x16_f16(ea, zb1, acc1, 0, 0, 0);
        }

        // in-register argmin over the 16 codes this lane holds
        #pragma unroll
        for (int reg = 0; reg < 16; ++reg) {
            int code = cb + (reg & 3) + 8 * (reg >> 2) + 4 * h;
            float cs = c_sq[code];
            float s0 = fmaf(-2.f, acc0[reg], cs);
            float s1 = fmaf(-2.f, acc1[reg], cs);
            kmin0 = min(kmin0, (int)(s0 * KEY_SCALE) * 1024 + code);
            kmin1 = min(kmin1, (int)(s1 * KEY_SCALE) * 1024 + code);
        }
    }

    // merge lane-halves (lanes m and m+32 hold the same z row, disjoint codes)
    kmin0 = min(kmin0, __shfl_xor(kmin0, 32));
    kmin1 = min(kmin1, __shfl_xor(kmin1, 32));
    if (h == 0) { bl_key[w][m] = kmin0; bl_key[w][32 + m] = kmin1; }
    __syncthreads();

    // ---- combine 8 waves -> device-scope atomicMin; cg0 writes zsq ----
    if (tid < 64) {
        int k = bl_key[0][tid];
        #pragma unroll
        for (int w2 = 1; w2 < 8; ++w2) k = min(k, bl_key[w2][tid]);
        atomicMin(&key_ws[n0 + tid], k);
        if (cg == 0) {
            float zq = 0.f;
            #pragma unroll
            for (int p = 0; p < 8; ++p) zq += zsq_part[p][tid];
            zsq_g[n0 + tid] = zq;
        }
    }
}

// ---------------------------------------------------------------------------
// K2: consumer. grid 1024 = (tile 0..511) x (channel-half 0..1), 512 threads.
// Reads final keys (plain loads; kernel boundary) -> idx; ch0 blocks own
// counts atomicAdd + loss (score_min from key + zsq_g). Transposed LDS stage
// Qt[128][65] (scatter writes and column drains both bank-conflict-free);
// each block writes 64 rows x 128 channels in full 256B lines. Last of 1024
// blocks finalizes loss + perplexity.
// ---------------------------------------------------------------------------
__global__ __launch_bounds__(512, 8)
void vq_out_kernel(const float* __restrict__ emb, const int* __restrict__ key_ws,
                   const float* __restrict__ zsq_g, int* __restrict__ counts,
                   float* __restrict__ loss64, unsigned* __restrict__ done,
                   float* __restrict__ out, float* __restrict__ out_tail) {
    __shared__ float Qt[128][65];   // 33280 B, transposed: [ch][row]
    __shared__ int   idx_s[64];
    __shared__ float wsum[8];
    __shared__ int   flag_s;

    const int tid = threadIdx.x;
    const int tile = blockIdx.x >> 1;
    const int ch0 = (blockIdx.x & 1) * 128;
    const int n0 = tile * 64;
    const int b = n0 >> 10;
    const int hw0 = n0 & 1023;

    if (tid < 64) {
        int k = key_ws[n0 + tid];
        int i = k & 1023;               // low 10 bits = code (two's complement safe)
        idx_s[tid] = i;
        if (ch0 == 0) {
            atomicAdd(&counts[i], 1);
            float lr = (float)(k >> 10) * KEY_INV + zsq_g[n0 + tid];
            #pragma unroll
            for (int off = 32; off > 0; off >>= 1) lr += __shfl_down(lr, off);
            if (tid == 0) atomicAdd(&loss64[tile & 63], lr);
        }
    }
    __syncthreads();

    // stage: thread (p=tid>>6, r=tid&63) loads emb[idx[r]][ch0+p*16..+16]
    // (coalesced 64B/lane from L2), scatters into Qt columns.
    {
        int r = tid & 63;
        int p = tid >> 6;
        const float* ep = emb + (size_t)idx_s[r] * DD + ch0 + p * 16;
        float4 v0 = *(const float4*)(ep);
        float4 v1 = *(const float4*)(ep + 4);
        float4 v2 = *(const float4*)(ep + 8);
        float4 v3 = *(const float4*)(ep + 12);
        float vv[16] = {v0.x, v0.y, v0.z, v0.w, v1.x, v1.y, v1.z, v1.w,
                        v2.x, v2.y, v2.z, v2.w, v3.x, v3.y, v3.z, v3.w};
        #pragma unroll
        for (int g = 0; g < 16; ++g)
            Qt[p * 16 + g][r] = vv[g];   // lanes r consecutive -> conflict-free
    }
    __syncthreads();

    // drain: wave w covers channels [w*16,(w+1)*16); per channel the 64 lanes
    // write one full 256B contiguous line of out.
    {
        int lane = tid & 63;
        int w = tid >> 6;
        const size_t base = (size_t)b * (DD * 1024) + hw0 + lane;
        #pragma unroll
        for (int g = 0; g < 16; ++g) {
            int ch = w * 16 + g;
            out[base + (size_t)(ch0 + ch) * 1024] = Qt[ch][lane];
        }
    }

    // ---- last-block finalize ----
    if (tid == 0) {
        __threadfence();
        flag_s = (atomicAdd(done, 1u) == 1023u) ? 1 : 0;
    }
    __syncthreads();
    if (flag_s) {
        float s = 0.f;
        for (int k = tid; k < KC; k += 512) {
            float pr = (float)counts[k] * (1.0f / (float)NROWS);
            s += pr * logf(pr + 1e-10f);
        }
        #pragma unroll
        for (int off = 32; off > 0; off >>= 1) s += __shfl_down(s, off);
        if ((tid & 63) == 0) wsum[tid >> 6] = s;
        __syncthreads();
        float loss_tot = 0.f;
        if (tid < 64) {
            float lv = loss64[tid];
            #pragma unroll
            for (int off = 32; off > 0; off >>= 1) lv += __shfl_down(lv, off);
            loss_tot = lv;              // lane 0 (tid 0) valid
        }
        if (tid == 0) {
            float ent = 0.f;
            #pragma unroll
            for (int p = 0; p < 8; ++p) ent += wsum[p];
            out_tail[0] = 1.25f * loss_tot * (1.0f / (float)NELEM);
            out_tail[1] = expf(-ent);
        }
    }
}

// ---------------------------------------------------------------------------
extern "C" void kernel_launch(void* const* d_in, const int* in_sizes, int n_in,
                              void* d_out, int out_size, void* d_ws, size_t ws_size,
                              hipStream_t stream) {
    const float* z = (const float*)d_in[0];    // (32,256,32,32)
    const float* emb = (const float*)d_in[1];  // (1024,256)
    float* out = (float*)d_out;                // 8388608 + 2

    char* wsb = (char*)d_ws;
    f16* emb_h = (f16*)wsb;                        // 524288 B
    float* c_sq = (float*)(wsb + 524288);          // 4096 B
    int* counts = (int*)(wsb + 528384);            // 4096 B
    float* loss64 = (float*)(wsb + 532480);        // 256 B
    unsigned* done = (unsigned*)(wsb + 532736);    // 4 B
    int* key_ws = (int*)(wsb + 535040);            // 131072 B
    float* zsq_g = (float*)(wsb + 666112);         // 131072 B

    hipLaunchKernelGGL(vq_prep_kernel, dim3(256), dim3(256), 0, stream,
                       emb, emb_h, c_sq, counts, loss64, done, key_ws);
    hipLaunchKernelGGL(vq_argmin_kernel, dim3(1024), dim3(512), 0, stream,
                       z, emb_h, c_sq, zsq_g, key_ws);
    hipLaunchKernelGGL(vq_out_kernel, dim3(1024), dim3(512), 0, stream,
                       emb, key_ws, zsq_g, counts, loss64, done, out, out + NELEM);
}

// Round 8
// 125.951 us; speedup vs baseline: 1.4073x; 1.2528x over previous
//
#include <hip/hip_runtime.h>
#include <math.h>

// Problem constants
#define KC 1024       // num codes
#define DD 256        // embedding dim
#define NROWS 32768   // 32 * 32 * 32 (B*H*W)
#define NELEM 8388608 // NROWS * DD

typedef _Float16 f16;
typedef __attribute__((ext_vector_type(8))) _Float16 f16x8;
typedef __attribute__((ext_vector_type(16))) float f32x16;

#define KEY_SCALE 2097152.0f   // 2^21; |score| <= ~0.63 -> |ikey| < 2^21
#define KEY_INV   (1.0f / 2097152.0f)

// ---------------------------------------------------------------------------
// prep: c_sq (exact fp32) + emb -> fp16 swizzled. Nothing to zero (the
// pipeline has NO global accumulators anymore). grid 256 x 256.
// emb_h layout: [kg 32][code 1024][8]
// ---------------------------------------------------------------------------
__global__ void vq_prep_kernel(const float* __restrict__ emb, f16* __restrict__ emb_h,
                               float* __restrict__ c_sq) {
    const int tid = threadIdx.x;
    const int gt = blockIdx.x * 256 + tid;
    {
        int k = blockIdx.x * 4 + (tid >> 6);
        int lane = tid & 63;
        float4 v = *(const float4*)(emb + (size_t)k * DD + lane * 4);
        float s = v.x * v.x + v.y * v.y + v.z * v.z + v.w * v.w;
        #pragma unroll
        for (int off = 32; off > 0; off >>= 1) s += __shfl_down(s, off);
        if (lane == 0) c_sq[k] = s;
    }
    if (gt < 32768) {
        int code = gt & 1023;
        int kg = gt >> 10;
        const float* p = emb + (size_t)code * DD + kg * 8;
        float4 v0 = *(const float4*)p;
        float4 v1 = *(const float4*)(p + 4);
        f16x8 hcv;
        hcv[0] = (f16)v0.x; hcv[1] = (f16)v0.y; hcv[2] = (f16)v0.z; hcv[3] = (f16)v0.w;
        hcv[4] = (f16)v1.x; hcv[5] = (f16)v1.y; hcv[6] = (f16)v1.z; hcv[7] = (f16)v1.w;
        *(f16x8*)(emb_h + (size_t)gt * 8) = hcv;
    }
}

// ---------------------------------------------------------------------------
// K1: argmin producer, swapped-operand MFMA, ZERO global atomics.
// grid 512, 512 threads (8 waves), 64 rows/block, ALL 1024 codes/block
// (no pair split -> no atomicMin; emb_h L2 draw 256MB aggregate and each
// emb fragment feeds BOTH z-row-tiles' MFMAs).
//   mfma(emb_frag, z_frag): D[code][zrow] -> lane = z row, reg = code.
//   Argmin over codes is in-register (16 mins/chunk, consumed immediately;
//   no key arrays, no butterflies) + one shfl_xor(32) half-merge.
// Outputs: idx_g (plain stores), loss_blk[bid] (PLAIN store).
// launch_bounds(512,4): grid caps occupancy at 2 blocks/CU anyway -> allow
// up to 128 regs, zero spill risk (R6 lesson: never force regs below state).
// argmin key = trunc(score*2^21)*1024 + code (monotone, first-min ties;
// identical op order to R7 -> bit-identical idx).
// loss per row: sum_c (q-z)^2 = score_min + ||z||^2.
// ---------------------------------------------------------------------------
__global__ __launch_bounds__(512, 4)
void vq_argmin_kernel(const float* __restrict__ z, const f16* __restrict__ emb_h,
                      const float* __restrict__ c_sq, int* __restrict__ idx_g,
                      float* __restrict__ loss_blk) {
    __shared__ __align__(16) f16 z_s[32 * 64 * 8];   // [kg 32][row 64][8] = 32768 B
    __shared__ int   bl_key[8][64];                   // 2048 B
    __shared__ float zsq_part[8][64];                 // 2048 B

    const int tid = threadIdx.x;
    const int n0 = blockIdx.x * 64;
    const int b = n0 >> 10;
    const int hw0 = n0 & 1023;

    // ---- Phase A: stage z tile fp16 + per-row ||z||^2 partials ----
    {
        const int r = tid & 63;
        const int kq = tid >> 6;  // 0..7
        const float* zp = z + (size_t)b * (DD * 1024) + hw0 + r;
        float sq = 0.f;
        #pragma unroll
        for (int it = 0; it < 4; ++it) {
            int kg = kq * 4 + it;
            f16x8 hv;
            #pragma unroll
            for (int j = 0; j < 8; ++j) {
                float v = zp[(size_t)(kg * 8 + j) * 1024];
                sq += v * v;
                hv[j] = (f16)v;
            }
            *(f16x8*)&z_s[(kg * 64 + r) * 8] = hv;
        }
        zsq_part[kq][r] = sq;
    }
    __syncthreads();

    const int m = tid & 31;        // lane -> z row (D col)
    const int h = (tid >> 5) & 1;  // k-half; also selects code subset (+4h)
    const int w = tid >> 6;        // wave id 0..7

    int kmin0 = 0x7FFFFFFF;        // running key, z rows m
    int kmin1 = 0x7FFFFFFF;        // running key, z rows m+32

    // ---- Phase B: wave owns 128 codes as 4 chunks of 32 ----
    for (int c = 0; c < 4; ++c) {
        const int cb = w * 128 + c * 32;               // chunk base code
        const f16* ebp = emb_h + (size_t)h * 8192 + (size_t)(cb + m) * 8;

        f32x16 acc0, acc1;   // D[code][row] for z rows 0-31 / 32-63
        #pragma unroll
        for (int i = 0; i < 16; ++i) { acc0[i] = 0.f; acc1[i] = 0.f; }

        #pragma unroll 2
        for (int ks = 0; ks < 16; ++ks) {
            const f16* za = z_s + ((size_t)(2 * ks + h) * 64 + m) * 8;
            f16x8 zb0 = *(const f16x8*)(za);           // z rows 0-31  (B frag)
            f16x8 zb1 = *(const f16x8*)(za + 256);     // z rows 32-63 (B frag)
            f16x8 ea  = *(const f16x8*)(ebp + (size_t)ks * 16384); // emb (A frag)
            acc0 = __builtin_amdgcn_mfma_f32_32x32x16_f16(ea, zb0, acc0, 0, 0, 0);
            acc1 = __builtin_amdgcn_mfma_f32_32x32x16_f16(ea, zb1, acc1, 0, 0, 0);
        }

        // in-register argmin over the 16 codes this lane holds
        #pragma unroll
        for (int reg = 0; reg < 16; ++reg) {
            int code = cb + (reg & 3) + 8 * (reg >> 2) + 4 * h;
            float cs = c_sq[code];
            float s0 = fmaf(-2.f, acc0[reg], cs);
            float s1 = fmaf(-2.f, acc1[reg], cs);
            kmin0 = min(kmin0, (int)(s0 * KEY_SCALE) * 1024 + code);
            kmin1 = min(kmin1, (int)(s1 * KEY_SCALE) * 1024 + code);
        }
    }

    // merge lane-halves (lanes m and m+32 hold the same z row, disjoint codes)
    kmin0 = min(kmin0, __shfl_xor(kmin0, 32));
    kmin1 = min(kmin1, __shfl_xor(kmin1, 32));
    if (h == 0) { bl_key[w][m] = kmin0; bl_key[w][32 + m] = kmin1; }
    __syncthreads();

    // ---- combine 8 waves -> idx store + per-block loss (plain stores) ----
    if (tid < 64) {
        int k = bl_key[0][tid];
        #pragma unroll
        for (int w2 = 1; w2 < 8; ++w2) k = min(k, bl_key[w2][tid]);
        idx_g[n0 + tid] = k & 1023;     // low 10 bits = code
        float zq = 0.f;
        #pragma unroll
        for (int p = 0; p < 8; ++p) zq += zsq_part[p][tid];
        float lr = (float)(k >> 10) * KEY_INV + zq;  // score_min + ||z||^2
        #pragma unroll
        for (int off = 32; off > 0; off >>= 1) lr += __shfl_down(lr, off);
        if (tid == 0) loss_blk[blockIdx.x] = lr;     // NO atomic
    }
}

// ---------------------------------------------------------------------------
// K2: grid 1025. Blocks 0..1023 = writers (tile x channel-half), R7's
// transposed LDS stage Qt[128][65], full 256B out lines — with ALL atomics
// and fences REMOVED. Block 1024 = finalize: depends only on K1 outputs
// (idx_g, loss_blk; coherent at kernel boundary) — LDS histogram of idx_g
// -> entropy; sum loss_blk -> loss. No done counter anywhere.
// ---------------------------------------------------------------------------
__global__ __launch_bounds__(512, 4)
void vq_out_kernel(const float* __restrict__ emb, const int* __restrict__ idx_g,
                   const float* __restrict__ loss_blk, float* __restrict__ out,
                   float* __restrict__ out_tail) {
    __shared__ float Qt[128][65];   // 33280 B, transposed: [ch][row]
    __shared__ int   idx_s[64];

    const int tid = threadIdx.x;

    if (blockIdx.x == 1024) {
        // ---- finalize block ----
        __shared__ int   hist[KC];      // aliases Qt region? no — separate is fine
        __shared__ float wsum[8];
        for (int k = tid; k < KC; k += 512) hist[k] = 0;
        __syncthreads();
        for (int i = tid; i < NROWS; i += 512)
            atomicAdd(&hist[idx_g[i]], 1);           // LDS atomic (cheap)
        __syncthreads();
        float s = 0.f;
        for (int k = tid; k < KC; k += 512) {
            float pr = (float)hist[k] * (1.0f / (float)NROWS);
            s += pr * logf(pr + 1e-10f);
        }
        float lv = (tid < 512) ? loss_blk[tid] : 0.f; // 512 partials, 1/thread
        s = s;  // entropy partial
        // reduce entropy and loss together across the block
        #pragma unroll
        for (int off = 32; off > 0; off >>= 1) {
            s  += __shfl_down(s, off);
            lv += __shfl_down(lv, off);
        }
        if ((tid & 63) == 0) { wsum[tid >> 6] = s; Qt[0][tid >> 6] = lv; }
        __syncthreads();
        if (tid == 0) {
            float ent = 0.f, loss_tot = 0.f;
            #pragma unroll
            for (int p = 0; p < 8; ++p) { ent += wsum[p]; loss_tot += Qt[0][p]; }
            out_tail[0] = 1.25f * loss_tot * (1.0f / (float)NELEM);
            out_tail[1] = expf(-ent);
        }
        return;
    }

    const int tile = blockIdx.x >> 1;
    const int ch0 = (blockIdx.x & 1) * 128;
    const int n0 = tile * 64;
    const int b = n0 >> 10;
    const int hw0 = n0 & 1023;

    if (tid < 64) idx_s[tid] = idx_g[n0 + tid];
    __syncthreads();

    // stage: thread (p=tid>>6, r=tid&63) loads emb[idx[r]][ch0+p*16..+16]
    // (coalesced 64B/lane from L2), scatters into Qt columns.
    {
        int r = tid & 63;
        int p = tid >> 6;
        const float* ep = emb + (size_t)idx_s[r] * DD + ch0 + p * 16;
        float4 v0 = *(const float4*)(ep);
        float4 v1 = *(const float4*)(ep + 4);
        float4 v2 = *(const float4*)(ep + 8);
        float4 v3 = *(const float4*)(ep + 12);
        float vv[16] = {v0.x, v0.y, v0.z, v0.w, v1.x, v1.y, v1.z, v1.w,
                        v2.x, v2.y, v2.z, v2.w, v3.x, v3.y, v3.z, v3.w};
        #pragma unroll
        for (int g = 0; g < 16; ++g)
            Qt[p * 16 + g][r] = vv[g];   // lanes r consecutive -> conflict-free
    }
    __syncthreads();

    // drain: wave w covers channels [w*16,(w+1)*16); per channel the 64 lanes
    // write one full 256B contiguous line of out. Then EXIT — no fence,
    // no atomic, no done counter.
    {
        int lane = tid & 63;
        int w = tid >> 6;
        const size_t base = (size_t)b * (DD * 1024) + hw0 + lane;
        #pragma unroll
        for (int g = 0; g < 16; ++g) {
            int ch = w * 16 + g;
            out[base + (size_t)(ch0 + ch) * 1024] = Qt[ch][lane];
        }
    }
}

// ---------------------------------------------------------------------------
extern "C" void kernel_launch(void* const* d_in, const int* in_sizes, int n_in,
                              void* d_out, int out_size, void* d_ws, size_t ws_size,
                              hipStream_t stream) {
    const float* z = (const float*)d_in[0];    // (32,256,32,32)
    const float* emb = (const float*)d_in[1];  // (1024,256)
    float* out = (float*)d_out;                // 8388608 + 2

    char* wsb = (char*)d_ws;
    f16* emb_h = (f16*)wsb;                        // 524288 B
    float* c_sq = (float*)(wsb + 524288);          // 4096 B
    int* idx_g = (int*)(wsb + 528384);             // 131072 B
    float* loss_blk = (float*)(wsb + 659456);      // 2048 B

    hipLaunchKernelGGL(vq_prep_kernel, dim3(256), dim3(256), 0, stream,
                       emb, emb_h, c_sq);
    hipLaunchKernelGGL(vq_argmin_kernel, dim3(512), dim3(512), 0, stream,
                       z, emb_h, c_sq, idx_g, loss_blk);
    hipLaunchKernelGGL(vq_out_kernel, dim3(1025), dim3(512), 0, stream,
                       emb, idx_g, loss_blk, out, out + NELEM);
}